// Round 15
// baseline (724.117 us; speedup 1.0000x reference)
//
#include <hip/hip_runtime.h>
#include <hip/hip_bf16.h>
#include <hip/hip_fp16.h>

#define N_NODES 100000
#define N_EDGES 3200000
#define N_GRAPHS 4096
#define N_REL 5
#define N_BASES 4
#define HID 32
#define SEG (N_NODES*N_REL)
#define DUMMY N_NODES            // extra node whose fp16 feature row is all-zero

#define NBUCK 392                // buckets of 256 dst nodes
#define BCAP  10240              // part-record capacity per bucket (mean 8163)
#define PBCAP 15360              // padded srcs capacity per bucket (mean ~12.9K)
#define NKEY  1280               // 256 nodes * 5 rels
#define PTILE 4096               // edges per k_part block (32 KB stage -> 4 blocks/CU)

typedef _Float16 half8 __attribute__((ext_vector_type(8)));
typedef float floatx4 __attribute__((ext_vector_type(4)));

// ---------------- CSR pass 1: partition edges into dst-range buckets ----------------
static __global__ __launch_bounds__(256) void k_part(const int* __restrict__ ei,
                                                     const int* __restrict__ et,
                                                     int* __restrict__ gcur,
                                                     unsigned long long* __restrict__ part) {
    __shared__ unsigned long long stage[PTILE];     // 32 KB
    __shared__ int hist[NBUCK];
    __shared__ int lofs[NBUCK];
    __shared__ int lbase[NBUCK];
    __shared__ int sscan[256];
    int t = threadIdx.x;
    int e0 = blockIdx.x * PTILE;
    int tile_n = N_EDGES - e0; if (tile_n > PTILE) tile_n = PTILE;

    for (int k = t; k < NBUCK; k += 256) hist[k] = 0;
    __syncthreads();
    // pass A: load 16 edges/thread into registers + LDS histogram
    int src[16], bkt[16], lkey[16];
#pragma unroll
    for (int j = 0; j < 16; j++) {
        int e = e0 + j * 256 + t;
        if (e < N_EDGES) {
            int s = ei[e];
            int d = ei[N_EDGES + e];
            int r = et[e];
            src[j] = s; bkt[j] = d >> 8; lkey[j] = ((d & 255) * 5) + r;
            atomicAdd(&hist[bkt[j]], 1);
        } else bkt[j] = -1;
    }
    __syncthreads();
    // exclusive scan over 392 buckets: thread t owns slots 2t, 2t+1
    int h0 = (2 * t     < NBUCK) ? hist[2 * t]     : 0;
    int h1 = (2 * t + 1 < NBUCK) ? hist[2 * t + 1] : 0;
    int s2 = h0 + h1;
    sscan[t] = s2;
    __syncthreads();
    for (int off = 1; off < 256; off <<= 1) {
        int xv = (t >= off) ? sscan[t - off] : 0;
        __syncthreads();
        sscan[t] += xv;
        __syncthreads();
    }
    int excl = sscan[t] - s2;
    if (2 * t     < NBUCK) lofs[2 * t]     = excl;
    if (2 * t + 1 < NBUCK) lofs[2 * t + 1] = excl + h0;
    for (int k = t; k < NBUCK; k += 256) lbase[k] = atomicAdd(&gcur[k], hist[k]);
    __syncthreads();
    for (int k = t; k < NBUCK; k += 256) hist[k] = 0;   // reuse as cursor
    __syncthreads();
    // pass B: scatter registers into bucket-ordered LDS staging
#pragma unroll
    for (int j = 0; j < 16; j++) {
        if (bkt[j] >= 0) {
            int rank = atomicAdd(&hist[bkt[j]], 1);
            stage[lofs[bkt[j]] + rank] =
                ((unsigned long long)(unsigned)((bkt[j] << 16) | lkey[j]) << 32)
                | (unsigned)src[j];
        }
    }
    __syncthreads();
    // pass C: sequential copy-out — per-bucket runs land coalesced
    for (int i = t; i < tile_n; i += 256) {
        unsigned long long u = stage[i];
        unsigned hi = (unsigned)(u >> 32);
        int bb = hi >> 16;
        unsigned long long lk = hi & 0xFFFFu;
        int pos = lbase[bb] + (i - lofs[bb]);
        if (pos < BCAP)
            part[(size_t)bb * BCAP + pos] = (lk << 32) | (u & 0xffffffffULL);
    }
}

// ---------------- CSR pass 2: per-bucket counting sort, runs PADDED to 8 ----------------
// Block 0 additionally writes the ht1..ht4 DUMMY rows at the END — part
// aliases ht1..ht4, so these zero rows must land only after part is consumed.
static __global__ __launch_bounds__(1024) void k_bsort(const unsigned long long* __restrict__ part,
                                                       const int* __restrict__ gcur,
                                                       int* __restrict__ offs,
                                                       int* __restrict__ cnt,
                                                       int* __restrict__ srcs,
                                                       __half* __restrict__ ht1,
                                                       __half* __restrict__ ht2,
                                                       __half* __restrict__ ht3,
                                                       __half* __restrict__ ht4) {
    __shared__ int lhist[NKEY];      // 5 KB
    __shared__ int lscan[NKEY];      // 5 KB
    __shared__ int sscan[256];       // 1 KB
    __shared__ int lsrc[PBCAP];      // 60 KB
    int b = blockIdx.x;
    int t = threadIdx.x;
    int n = gcur[b]; if (n > BCAP) n = BCAP;
    const unsigned long long* reg = part + (size_t)b * BCAP;

    for (int k = t; k < NKEY; k += 1024) lhist[k] = 0;
    __syncthreads();
    for (int i = t; i < n; i += 1024)
        atomicAdd(&lhist[(int)(reg[i] >> 32)], 1);
    __syncthreads();

    // exclusive scan over PADDED counts (1280 = 256 threads x 5 keys)
    int loc[5]; int s5 = 0;
    if (t < 256) {
#pragma unroll
        for (int j = 0; j < 5; j++) { loc[j] = s5; s5 += (lhist[t * 5 + j] + 7) & ~7; }
        sscan[t] = s5;
    }
    __syncthreads();
    for (int off = 1; off < 256; off <<= 1) {
        int x = (t >= off && t < 256) ? sscan[t - off] : 0;
        __syncthreads();
        if (t < 256) sscan[t] += x;
        __syncthreads();
    }
    if (t < 256) {
        int excl = sscan[t] - s5;
#pragma unroll
        for (int j = 0; j < 5; j++) lscan[t * 5 + j] = excl + loc[j];
    }
    __syncthreads();
    int ptot = sscan[255]; if (ptot > PBCAP) ptot = PBCAP;
    int pout = ptot + 16; if (pout > PBCAP) pout = PBCAP;

    int base = b * PBCAP;
    if (t < 256) {
#pragma unroll
        for (int j = 0; j < 5; j++) {
            int k = t * 5 + j;
            int segid = b * NKEY + k;
            if (segid < SEG) {
                cnt[segid]  = lhist[k];
                offs[segid] = base + lscan[k];
            }
        }
    }
    __syncthreads();
    // reset cursors + dummy-fill the written region
    for (int k = t; k < NKEY; k += 1024) lhist[k] = 0;
    for (int i = t; i < pout; i += 1024) lsrc[i] = DUMMY;
    __syncthreads();
    for (int i = t; i < n; i += 1024) {
        unsigned long long u = reg[i];
        int k = (int)(u >> 32);
        int pos = lscan[k] + atomicAdd(&lhist[k], 1);
        if (pos < PBCAP) lsrc[pos] = (int)(u & 0xffffffffULL);
    }
    __syncthreads();
    for (int i = t; i < pout; i += 1024) srcs[base + i] = lsrc[i];

    // ht1..ht4 DUMMY rows — safe here: this block's part reads are done, and
    // k_layer (which consumes them) launches after this kernel completes.
    if (b == 0 && t < 128) {
        __half* hp = (t < 32) ? ht1 : (t < 64) ? ht2 : (t < 96) ? ht3 : ht4;
        hp[N_NODES * 32 + (t & 31)] = __float2half(0.f);
    }
}

// ---------------- fused prep: x->ht0 (+its dummy row), srcs slack, gcur zero,
// ---------------- RGCN B-frags (Wb), MLP B-frags (Wm) — one launch ----------------
// NOTE: ht1..ht4 dummy rows are NOT written here — they alias `part` (written
// later by k_part); k_bsort writes them after consuming part. (R14's bug.)
static __global__ __launch_bounds__(256) void k_prep(
    const float* __restrict__ x, __half* __restrict__ ht0,
    int* __restrict__ srcs, int* __restrict__ gcur,
    const float* __restrict__ ba0, const float* __restrict__ ro0,
    const float* __restrict__ ba1, const float* __restrict__ ro1,
    const float* __restrict__ ba2, const float* __restrict__ ro2,
    const float* __restrict__ ba3, const float* __restrict__ ro3,
    const float* __restrict__ w1, __half* __restrict__ Wb,
    __half* __restrict__ Wm) {
    int blk = blockIdx.x;
    int t = threadIdx.x;
    if (blk < 12501) {                              // ht0 + its dummy row + slack
        int tid = blk * 256 + t;
        if (tid < (N_NODES + 1) * 32) {
            int nd = tid >> 5, ii = tid & 31;
            float v = (nd < N_NODES && ii < 4) ? x[(nd << 2) + ii] : 0.f;
            ht0[tid] = __float2half(v);
        } else {
            int r = tid - (N_NODES + 1) * 32;
            if (r < 16) srcs[NBUCK * PBCAP + r] = DUMMY;   // global slack
        }
    } else if (blk < 12581) {                       // Wb: 80 blocks = 20480
        int idx = (blk - 12501) * 256 + t;
        int j    = idx & 7;
        int lane = (idx >> 3) & 63;
        int tile = (idx >> 9) & 1;
        int ls   = idx >> 10;                       // l*5 + s, < 20
        int l    = ls / 5;
        int s    = ls - l * 5;
        const float* basis = (l == 0) ? ba0 : (l == 1) ? ba1 : (l == 2) ? ba2 : ba3;
        const float* root  = (l == 0) ? ro0 : (l == 1) ? ro1 : (l == 2) ? ro2 : ro3;
        int in_c = (l == 0) ? 4 : HID;
        int k = s * 32 + ((lane >> 4) << 3) + j;
        int o = tile * 16 + (lane & 15);
        float v;
        if (k < 128) {
            int b = k >> 5, ii = k & 31;
            v = (ii < in_c) ? basis[(b * in_c + ii) * HID + o] : 0.f;
        } else {
            int ii = k - 128;
            v = (ii < in_c) ? root[ii * HID + o] : 0.f;
        }
        Wb[idx] = __float2half(v);
    } else if (blk < 12709) {                       // Wm: 128 blocks = 32768
        int idx = (blk - 12581) * 256 + t;
        int j    = idx & 7;
        int lane = (idx >> 3) & 63;
        int s    = (idx >> 9) & 7;
        int tile = idx >> 12;
        int k = s * 32 + ((lane >> 4) << 3) + j;
        int o = tile * 16 + (lane & 15);
        Wm[idx] = __float2half(w1[k * 128 + o]);
    } else {                                        // gcur zero
        for (int k = t; k < NBUCK; k += 256) gcur[k] = 0;
    }
}

// ---------------- fused RGCN layer ----------------
// Phase 1: quarter-wave = 1 node, p = dim pair, __half2 dword gathers from a
// DENSE fp16 table (stride 32). All 5 relation runs' first batches (10 srcs
// dwordx4 + 40 gathers) issued before any consumption — the 5-run serial
// latency chain collapses to ~1 exposed round. Residual batches (~19%)
// follow. Fold per run; MFMA phase 2 unchanged.
static __global__ __launch_bounds__(256, 8) void k_layer(
    const __half2* __restrict__ tab, const int* __restrict__ offs,
    const int* __restrict__ cnt, const int* __restrict__ srcs,
    const float* __restrict__ comp, const __half* __restrict__ Wbl,
    const float* __restrict__ bias, __half* __restrict__ hout) {
    __shared__ __align__(16) __half sAgg16[16 * 176];   // 5.5 KB
    int t = threadIdx.x;
    int wave = t >> 6, q = (t >> 4) & 3, p = t & 15;

    float4 cw0 = *(const float4*)(comp + 0);        // SGPR-resident
    float4 cw1 = *(const float4*)(comp + 4);
    float4 cw2 = *(const float4*)(comp + 8);
    float4 cw3 = *(const float4*)(comp + 12);
    float4 cw4 = *(const float4*)(comp + 16);

    int n = blockIdx.x * 16 + wave * 4 + q;         // N_NODES = 6250*16
    int s5 = n * N_REL;
    int oo[6], cc[5];
#pragma unroll
    for (int r = 0; r < 5; r++) { oo[r] = offs[s5 + r]; cc[r] = cnt[s5 + r]; }
    oo[5] = oo[4] + ((cc[4] + 7) & ~7);             // padded end

    __half2 selfh = tab[n * 16 + p];

    // ---- first batches of ALL runs: 10 independent dwordx4 srcs loads ----
    int4 e0[5], e1[5];
#pragma unroll
    for (int r = 0; r < 5; r++) {
        const int4* sp4 = (const int4*)(srcs + oo[r]);
        e0[r] = sp4[0];
        e1[r] = sp4[1];
    }
    // ---- 40 gathers, all independent once e-loads land ----
    float Sx[5], Sy[5];
#pragma unroll
    for (int r = 0; r < 5; r++) {
        __half2 g0 = tab[e0[r].x * 16 + p], g1 = tab[e0[r].y * 16 + p];
        __half2 g2 = tab[e0[r].z * 16 + p], g3 = tab[e0[r].w * 16 + p];
        __half2 g4 = tab[e1[r].x * 16 + p], g5 = tab[e1[r].y * 16 + p];
        __half2 g6 = tab[e1[r].z * 16 + p], g7 = tab[e1[r].w * 16 + p];
        __half2 sb = __hadd2(__hadd2(__hadd2(g0, g1), __hadd2(g2, g3)),
                             __hadd2(__hadd2(g4, g5), __hadd2(g6, g7)));
        float2 bf = __half22float2(sb);
        Sx[r] = bf.x; Sy[r] = bf.y;
    }
    // ---- residual batches (runs longer than 8; ~19%) ----
#pragma unroll
    for (int r = 0; r < 5; r++) {
        int pr = oo[r + 1] - oo[r];
        const int* sp = srcs + oo[r];
        for (int s8 = 8; s8 < pr; s8 += 8) {
            int4 f0 = *(const int4*)(sp + s8);
            int4 f1 = *(const int4*)(sp + s8 + 4);
            __half2 h0 = tab[f0.x * 16 + p], h1 = tab[f0.y * 16 + p];
            __half2 h2 = tab[f0.z * 16 + p], h3 = tab[f0.w * 16 + p];
            __half2 h4 = tab[f1.x * 16 + p], h5 = tab[f1.y * 16 + p];
            __half2 h6 = tab[f1.z * 16 + p], h7 = tab[f1.w * 16 + p];
            __half2 rb = __hadd2(__hadd2(__hadd2(h0, h1), __hadd2(h2, h3)),
                                 __hadd2(__hadd2(h4, h5), __hadd2(h6, h7)));
            float2 rf = __half22float2(rb);
            Sx[r] += rf.x; Sy[r] += rf.y;
        }
    }
    // ---- per-run comp fold ----
    float a0x = 0.f, a0y = 0.f, a1x = 0.f, a1y = 0.f;
    float a2x = 0.f, a2y = 0.f, a3x = 0.f, a3y = 0.f;
#pragma unroll
    for (int r = 0; r < 5; r++) {
        int cr = cc[r];
        float ic = (cr > 0) ? __builtin_amdgcn_rcpf((float)cr) : 0.f;
        float scx = Sx[r] * ic, scy = Sy[r] * ic;
        float4 cw = (r == 0) ? cw0 : (r == 1) ? cw1 : (r == 2) ? cw2
                  : (r == 3) ? cw3 : cw4;           // resolved at unroll
        a0x += cw.x * scx; a0y += cw.x * scy;
        a1x += cw.y * scx; a1y += cw.y * scy;
        a2x += cw.z * scx; a2y += cw.z * scy;
        a3x += cw.w * scx; a3y += cw.w * scy;
    }
    int nl = wave * 4 + q;
    __half2* row = (__half2*)(sAgg16 + nl * 176);   // k/2 index
    row[p]      = __float22half2_rn(make_float2(a0x, a0y));   // k = 0..31
    row[16 + p] = __float22half2_rn(make_float2(a1x, a1y));   // k = 32..63
    row[32 + p] = __float22half2_rn(make_float2(a2x, a2y));   // k = 64..95
    row[48 + p] = __float22half2_rn(make_float2(a3x, a3y));   // k = 96..127
    row[64 + p] = selfh;                                      // k = 128..159
    __syncthreads();

    // phase 2: [16x160] x [160x32] via 5x mfma_f32_16x16x32_f16 per tile
    if (wave < 2) {
        int lane = t & 63;
        floatx4 acc = {0.f, 0.f, 0.f, 0.f};
        const __half* aBase = sAgg16 + (lane & 15) * 176 + ((lane >> 4) << 3);
        const __half* bBase = Wbl + wave * 512 + lane * 8;
#pragma unroll
        for (int s = 0; s < 5; s++) {
            half8 a = *(const half8*)(aBase + s * 32);
            half8 b = *(const half8*)(bBase + s * 1024);
            acc = __builtin_amdgcn_mfma_f32_16x16x32_f16(a, b, acc, 0, 0, 0);
        }
        int o = wave * 16 + (lane & 15);
        float bi = bias[o];
#pragma unroll
        for (int r = 0; r < 4; r++) {
            int node = blockIdx.x * 16 + ((lane >> 4) << 2) + r;
            hout[node * 32 + o] = __float2half(tanhf(acc[r] + bi));
        }
    }
}

// ---------------- final MLP via MFMA: 16 graphs/block ----------------
static __global__ __launch_bounds__(256) void k_mlp(
    const __half* __restrict__ h1, const __half* __restrict__ h2,
    const __half* __restrict__ h3, const __half* __restrict__ h4,
    const int* __restrict__ uidx, const int* __restrict__ iidx,
    const __half* __restrict__ Wm, const float* __restrict__ b1,
    const float* __restrict__ w2, const float* __restrict__ b2,
    float* __restrict__ out) {
    __shared__ __align__(16) __half sg[16 * 264];   // 8.25 KB
    __shared__ float sacc[4][16];
    int t = threadIdx.x, wave = t >> 6, lane = t & 63;
    int g0 = blockIdx.x * 16;
    int lt = lane >> 4, lp = lane & 15;
    const __half* htab = (lt == 0) ? h1 : (lt == 1) ? h2 : (lt == 2) ? h3 : h4;
#pragma unroll
    for (int gg2 = 0; gg2 < 4; gg2++) {
        int gg = wave * 4 + gg2;
        int g = g0 + gg;
        int u = uidx[g], it = iidx[g];
        __half2* dst = (__half2*)(sg + gg * 264);
        dst[lt * 16 + lp]      = ((const __half2*)(htab + u * 32))[lp];
        dst[64 + lt * 16 + lp] = ((const __half2*)(htab + it * 32))[lp];
    }
    __syncthreads();
    floatx4 acc0 = {0.f, 0.f, 0.f, 0.f}, acc1 = {0.f, 0.f, 0.f, 0.f};
    const __half* aBase = sg + (lane & 15) * 264 + ((lane >> 4) << 3);
    const __half* bB0 = Wm + (wave * 2 + 0) * 4096 + lane * 8;
    const __half* bB1 = Wm + (wave * 2 + 1) * 4096 + lane * 8;
#pragma unroll
    for (int s = 0; s < 8; s++) {
        half8 a  = *(const half8*)(aBase + s * 32);
        half8 f0 = *(const half8*)(bB0 + s * 512);
        half8 f1 = *(const half8*)(bB1 + s * 512);
        acc0 = __builtin_amdgcn_mfma_f32_16x16x32_f16(a, f0, acc0, 0, 0, 0);
        acc1 = __builtin_amdgcn_mfma_f32_16x16x32_f16(a, f1, acc1, 0, 0, 0);
    }
    int o0 = wave * 32 + (lane & 15);
    int o1 = o0 + 16;
    float b10 = b1[o0], b11 = b1[o1], w20 = w2[o0], w21 = w2[o1];
#pragma unroll
    for (int r = 0; r < 4; r++) {
        float z0 = fmaxf(acc0[r] + b10, 0.f);
        float z1 = fmaxf(acc1[r] + b11, 0.f);
        float v = z0 * w20 + z1 * w21;
#pragma unroll
        for (int off = 1; off < 16; off <<= 1) v += __shfl_xor(v, off);
        if ((lane & 15) == 0) sacc[wave][((lane >> 4) << 2) + r] = v;
    }
    __syncthreads();
    if (t < 16)
        out[g0 + t] = sacc[0][t] + sacc[1][t] + sacc[2][t] + sacc[3][t] + b2[0];
}

// ---------------- launcher ----------------
extern "C" void kernel_launch(void* const* d_in, const int* in_sizes, int n_in,
                              void* d_out, int out_size, void* d_ws, size_t ws_size,
                              hipStream_t stream) {
    const float* x  = (const float*)d_in[0];
    const int*   ei = (const int*)d_in[1];
    const int*   et = (const int*)d_in[2];
    const int*   ui = (const int*)d_in[3];
    const int*   ii = (const int*)d_in[4];
    const float* w1 = (const float*)d_in[21];
    const float* b1 = (const float*)d_in[22];
    const float* w2 = (const float*)d_in[23];
    const float* b2 = (const float*)d_in[24];

    // workspace layout (bytes, 128-aligned). Total ~60.2 MB; guard proven in R1.
    char* ws = (char*)d_ws;
    if (ws_size < 92167680UL) return;
    int*    gcur = (int*)(ws + 0);              // [392]
    int*    offs = (int*)(ws + 2048);           // [500000]
    int*    cnt  = (int*)(ws + 2002176);        // [500000]
    int*    srcs = (int*)(ws + 4002304);        // [392*15360] + 16 slack
    __half* Wb   = (__half*)(ws + 28086912);    // [20480] fp16 RGCN B-frags
    __half* Wm   = (__half*)(ws + 28127872);    // [32768] fp16 MLP B-frags
    __half* ht0  = (__half*)(ws + 28193536);    // [100001*32] fp16 dense
    __half* ht1  = (__half*)(ws + 34593664);    // [100001*32]
    __half* ht2  = (__half*)(ws + 40993792);    // [100001*32]
    __half* ht3  = (__half*)(ws + 47393920);    // [100001*32]
    __half* ht4  = (__half*)(ws + 53794048);    // [100001*32], ends 60.2 MB
    // part aliases ht1..ht4 + tail (dead after k_bsort; layers run later)
    unsigned long long* part = (unsigned long long*)(ws + 34593664);  // 32.1 MB

    // k_prep covers: ht0/slack (12501), Wb (80), Wm (128), gcur (1)
    k_prep<<<12710, 256, 0, stream>>>(x, ht0, srcs, gcur,
        (const float*)d_in[5],  (const float*)d_in[7],
        (const float*)d_in[9],  (const float*)d_in[11],
        (const float*)d_in[13], (const float*)d_in[15],
        (const float*)d_in[17], (const float*)d_in[19], w1, Wb, Wm);
    k_part<<<(N_EDGES + PTILE - 1) / PTILE, 256, 0, stream>>>(ei, et, gcur, part);
    k_bsort<<<NBUCK, 1024, 0, stream>>>(part, gcur, offs, cnt, srcs,
                                        ht1, ht2, ht3, ht4);

    __half* tabs[5] = {ht0, ht1, ht2, ht3, ht4};
    for (int l = 0; l < 4; l++) {
        const float* comp = (const float*)d_in[6 + 4 * l];
        const float* bias = (const float*)d_in[8 + 4 * l];
        k_layer<<<6250, 256, 0, stream>>>((const __half2*)tabs[l], offs, cnt,
                                          srcs, comp, Wb + l * 5120, bias,
                                          tabs[l + 1]);
    }
    k_mlp<<<256, 256, 0, stream>>>(ht1, ht2, ht3, ht4, ui, ii, Wm, b1, w2, b2,
                                   (float*)d_out);
}

// Round 16
// 532.879 us; speedup vs baseline: 1.3589x; 1.3589x over previous
//
#include <hip/hip_runtime.h>
#include <hip/hip_bf16.h>
#include <hip/hip_fp16.h>

#define N_NODES 100000
#define N_EDGES 3200000
#define N_GRAPHS 4096
#define N_REL 5
#define N_BASES 4
#define HID 32
#define SEG (N_NODES*N_REL)
#define DUMMY N_NODES            // extra node whose fp16 feature row is all-zero

#define NBUCK 392                // buckets of 256 dst nodes
#define BCAP  10240              // part-record capacity per bucket (mean 8163)
#define PBCAP 15360              // padded srcs capacity per bucket (mean ~12.9K)
#define NKEY  1280               // 256 nodes * 5 rels
#define PTILE 4096               // edges per k_part block (32 KB stage -> 4 blocks/CU)

typedef _Float16 half8 __attribute__((ext_vector_type(8)));
typedef float floatx4 __attribute__((ext_vector_type(4)));

// ---------------- CSR pass 1: partition edges into dst-range buckets ----------------
static __global__ __launch_bounds__(256) void k_part(const int* __restrict__ ei,
                                                     const int* __restrict__ et,
                                                     int* __restrict__ gcur,
                                                     unsigned long long* __restrict__ part) {
    __shared__ unsigned long long stage[PTILE];     // 32 KB
    __shared__ int hist[NBUCK];
    __shared__ int lofs[NBUCK];
    __shared__ int lbase[NBUCK];
    __shared__ int sscan[256];
    int t = threadIdx.x;
    int e0 = blockIdx.x * PTILE;
    int tile_n = N_EDGES - e0; if (tile_n > PTILE) tile_n = PTILE;

    for (int k = t; k < NBUCK; k += 256) hist[k] = 0;
    __syncthreads();
    // pass A: load 16 edges/thread into registers + LDS histogram
    int src[16], bkt[16], lkey[16];
#pragma unroll
    for (int j = 0; j < 16; j++) {
        int e = e0 + j * 256 + t;
        if (e < N_EDGES) {
            int s = ei[e];
            int d = ei[N_EDGES + e];
            int r = et[e];
            src[j] = s; bkt[j] = d >> 8; lkey[j] = ((d & 255) * 5) + r;
            atomicAdd(&hist[bkt[j]], 1);
        } else bkt[j] = -1;
    }
    __syncthreads();
    // exclusive scan over 392 buckets: thread t owns slots 2t, 2t+1
    int h0 = (2 * t     < NBUCK) ? hist[2 * t]     : 0;
    int h1 = (2 * t + 1 < NBUCK) ? hist[2 * t + 1] : 0;
    int s2 = h0 + h1;
    sscan[t] = s2;
    __syncthreads();
    for (int off = 1; off < 256; off <<= 1) {
        int xv = (t >= off) ? sscan[t - off] : 0;
        __syncthreads();
        sscan[t] += xv;
        __syncthreads();
    }
    int excl = sscan[t] - s2;
    if (2 * t     < NBUCK) lofs[2 * t]     = excl;
    if (2 * t + 1 < NBUCK) lofs[2 * t + 1] = excl + h0;
    for (int k = t; k < NBUCK; k += 256) lbase[k] = atomicAdd(&gcur[k], hist[k]);
    __syncthreads();
    for (int k = t; k < NBUCK; k += 256) hist[k] = 0;   // reuse as cursor
    __syncthreads();
    // pass B: scatter registers into bucket-ordered LDS staging
#pragma unroll
    for (int j = 0; j < 16; j++) {
        if (bkt[j] >= 0) {
            int rank = atomicAdd(&hist[bkt[j]], 1);
            stage[lofs[bkt[j]] + rank] =
                ((unsigned long long)(unsigned)((bkt[j] << 16) | lkey[j]) << 32)
                | (unsigned)src[j];
        }
    }
    __syncthreads();
    // pass C: sequential copy-out — per-bucket runs land coalesced
    for (int i = t; i < tile_n; i += 256) {
        unsigned long long u = stage[i];
        unsigned hi = (unsigned)(u >> 32);
        int bb = hi >> 16;
        unsigned long long lk = hi & 0xFFFFu;
        int pos = lbase[bb] + (i - lofs[bb]);
        if (pos < BCAP)
            part[(size_t)bb * BCAP + pos] = (lk << 32) | (u & 0xffffffffULL);
    }
}

// ---------------- CSR pass 2: per-bucket counting sort, runs PADDED to 8 ----------------
// Block 0 additionally writes the ht1..ht4 DUMMY rows at the END — part
// aliases ht1..ht4, so these zero rows must land only after part is consumed.
static __global__ __launch_bounds__(1024) void k_bsort(const unsigned long long* __restrict__ part,
                                                       const int* __restrict__ gcur,
                                                       int* __restrict__ offs,
                                                       int* __restrict__ cnt,
                                                       int* __restrict__ srcs,
                                                       __half* __restrict__ ht1,
                                                       __half* __restrict__ ht2,
                                                       __half* __restrict__ ht3,
                                                       __half* __restrict__ ht4) {
    __shared__ int lhist[NKEY];      // 5 KB
    __shared__ int lscan[NKEY];      // 5 KB
    __shared__ int sscan[256];       // 1 KB
    __shared__ int lsrc[PBCAP];      // 60 KB
    int b = blockIdx.x;
    int t = threadIdx.x;
    int n = gcur[b]; if (n > BCAP) n = BCAP;
    const unsigned long long* reg = part + (size_t)b * BCAP;

    for (int k = t; k < NKEY; k += 1024) lhist[k] = 0;
    __syncthreads();
    for (int i = t; i < n; i += 1024)
        atomicAdd(&lhist[(int)(reg[i] >> 32)], 1);
    __syncthreads();

    // exclusive scan over PADDED counts (1280 = 256 threads x 5 keys)
    int loc[5]; int s5 = 0;
    if (t < 256) {
#pragma unroll
        for (int j = 0; j < 5; j++) { loc[j] = s5; s5 += (lhist[t * 5 + j] + 7) & ~7; }
        sscan[t] = s5;
    }
    __syncthreads();
    for (int off = 1; off < 256; off <<= 1) {
        int x = (t >= off && t < 256) ? sscan[t - off] : 0;
        __syncthreads();
        if (t < 256) sscan[t] += x;
        __syncthreads();
    }
    if (t < 256) {
        int excl = sscan[t] - s5;
#pragma unroll
        for (int j = 0; j < 5; j++) lscan[t * 5 + j] = excl + loc[j];
    }
    __syncthreads();
    int ptot = sscan[255]; if (ptot > PBCAP) ptot = PBCAP;
    int pout = ptot + 16; if (pout > PBCAP) pout = PBCAP;

    int base = b * PBCAP;
    if (t < 256) {
#pragma unroll
        for (int j = 0; j < 5; j++) {
            int k = t * 5 + j;
            int segid = b * NKEY + k;
            if (segid < SEG) {
                cnt[segid]  = lhist[k];
                offs[segid] = base + lscan[k];
            }
        }
    }
    __syncthreads();
    // reset cursors + dummy-fill the written region
    for (int k = t; k < NKEY; k += 1024) lhist[k] = 0;
    for (int i = t; i < pout; i += 1024) lsrc[i] = DUMMY;
    __syncthreads();
    for (int i = t; i < n; i += 1024) {
        unsigned long long u = reg[i];
        int k = (int)(u >> 32);
        int pos = lscan[k] + atomicAdd(&lhist[k], 1);
        if (pos < PBCAP) lsrc[pos] = (int)(u & 0xffffffffULL);
    }
    __syncthreads();
    for (int i = t; i < pout; i += 1024) srcs[base + i] = lsrc[i];

    // ht1..ht4 DUMMY rows — safe here: this block's part reads are done, and
    // k_layer (which consumes them) launches after this kernel completes.
    if (b == 0 && t < 128) {
        __half* hp = (t < 32) ? ht1 : (t < 64) ? ht2 : (t < 96) ? ht3 : ht4;
        hp[N_NODES * 32 + (t & 31)] = __float2half(0.f);
    }
}

// ---------------- fused prep: x->ht0 (+its dummy row), srcs slack, gcur zero,
// ---------------- RGCN B-frags (Wb), MLP B-frags (Wm) — one launch ----------------
// NOTE: ht1..ht4 dummy rows are NOT written here — they alias `part` (written
// later by k_part); k_bsort writes them after consuming part.
static __global__ __launch_bounds__(256) void k_prep(
    const float* __restrict__ x, __half* __restrict__ ht0,
    int* __restrict__ srcs, int* __restrict__ gcur,
    const float* __restrict__ ba0, const float* __restrict__ ro0,
    const float* __restrict__ ba1, const float* __restrict__ ro1,
    const float* __restrict__ ba2, const float* __restrict__ ro2,
    const float* __restrict__ ba3, const float* __restrict__ ro3,
    const float* __restrict__ w1, __half* __restrict__ Wb,
    __half* __restrict__ Wm) {
    int blk = blockIdx.x;
    int t = threadIdx.x;
    if (blk < 12501) {                              // ht0 + its dummy row + slack
        int tid = blk * 256 + t;
        if (tid < (N_NODES + 1) * 32) {
            int nd = tid >> 5, ii = tid & 31;
            float v = (nd < N_NODES && ii < 4) ? x[(nd << 2) + ii] : 0.f;
            ht0[tid] = __float2half(v);
        } else {
            int r = tid - (N_NODES + 1) * 32;
            if (r < 16) srcs[NBUCK * PBCAP + r] = DUMMY;   // global slack
        }
    } else if (blk < 12581) {                       // Wb: 80 blocks = 20480
        int idx = (blk - 12501) * 256 + t;
        int j    = idx & 7;
        int lane = (idx >> 3) & 63;
        int tile = (idx >> 9) & 1;
        int ls   = idx >> 10;                       // l*5 + s, < 20
        int l    = ls / 5;
        int s    = ls - l * 5;
        const float* basis = (l == 0) ? ba0 : (l == 1) ? ba1 : (l == 2) ? ba2 : ba3;
        const float* root  = (l == 0) ? ro0 : (l == 1) ? ro1 : (l == 2) ? ro2 : ro3;
        int in_c = (l == 0) ? 4 : HID;
        int k = s * 32 + ((lane >> 4) << 3) + j;
        int o = tile * 16 + (lane & 15);
        float v;
        if (k < 128) {
            int b = k >> 5, ii = k & 31;
            v = (ii < in_c) ? basis[(b * in_c + ii) * HID + o] : 0.f;
        } else {
            int ii = k - 128;
            v = (ii < in_c) ? root[ii * HID + o] : 0.f;
        }
        Wb[idx] = __float2half(v);
    } else if (blk < 12709) {                       // Wm: 128 blocks = 32768
        int idx = (blk - 12581) * 256 + t;
        int j    = idx & 7;
        int lane = (idx >> 3) & 63;
        int s    = (idx >> 9) & 7;
        int tile = idx >> 12;
        int k = s * 32 + ((lane >> 4) << 3) + j;
        int o = tile * 16 + (lane & 15);
        Wm[idx] = __float2half(w1[k * 128 + o]);
    } else {                                        // gcur zero
        for (int k = t; k < NBUCK; k += 256) gcur[k] = 0;
    }
}

// ---------------- fused RGCN layer ----------------
// Phase 1: quarter-wave = 1 node, p = dim pair, __half2 dword gathers from a
// DENSE fp16 table (stride 32). All 5 relation runs' first batches (10 srcs
// dwordx4 + 40 gathers) issued before any consumption. R15 lesson: this needs
// ~80 live VGPRs — __launch_bounds__(256,6) gives an ~84-VGPR budget (R15's
// (256,8) capped at 64 and spilled ~290 MB of scratch traffic per dispatch).
static __global__ __launch_bounds__(256, 6) void k_layer(
    const __half2* __restrict__ tab, const int* __restrict__ offs,
    const int* __restrict__ cnt, const int* __restrict__ srcs,
    const float* __restrict__ comp, const __half* __restrict__ Wbl,
    const float* __restrict__ bias, __half* __restrict__ hout) {
    __shared__ __align__(16) __half sAgg16[16 * 176];   // 5.5 KB
    int t = threadIdx.x;
    int wave = t >> 6, q = (t >> 4) & 3, p = t & 15;

    float4 cw0 = *(const float4*)(comp + 0);        // SGPR-resident
    float4 cw1 = *(const float4*)(comp + 4);
    float4 cw2 = *(const float4*)(comp + 8);
    float4 cw3 = *(const float4*)(comp + 12);
    float4 cw4 = *(const float4*)(comp + 16);

    int n = blockIdx.x * 16 + wave * 4 + q;         // N_NODES = 6250*16
    int s5 = n * N_REL;
    int oo[6], cc[5];
#pragma unroll
    for (int r = 0; r < 5; r++) { oo[r] = offs[s5 + r]; cc[r] = cnt[s5 + r]; }
    oo[5] = oo[4] + ((cc[4] + 7) & ~7);             // padded end

    __half2 selfh = tab[n * 16 + p];

    // ---- first batches of ALL runs: 10 independent dwordx4 srcs loads ----
    int4 e0[5], e1[5];
#pragma unroll
    for (int r = 0; r < 5; r++) {
        const int4* sp4 = (const int4*)(srcs + oo[r]);
        e0[r] = sp4[0];
        e1[r] = sp4[1];
    }
    // ---- 40 gathers, all independent once e-loads land ----
    float Sx[5], Sy[5];
#pragma unroll
    for (int r = 0; r < 5; r++) {
        __half2 g0 = tab[e0[r].x * 16 + p], g1 = tab[e0[r].y * 16 + p];
        __half2 g2 = tab[e0[r].z * 16 + p], g3 = tab[e0[r].w * 16 + p];
        __half2 g4 = tab[e1[r].x * 16 + p], g5 = tab[e1[r].y * 16 + p];
        __half2 g6 = tab[e1[r].z * 16 + p], g7 = tab[e1[r].w * 16 + p];
        __half2 sb = __hadd2(__hadd2(__hadd2(g0, g1), __hadd2(g2, g3)),
                             __hadd2(__hadd2(g4, g5), __hadd2(g6, g7)));
        float2 bf = __half22float2(sb);
        Sx[r] = bf.x; Sy[r] = bf.y;
    }
    // ---- residual batches (runs longer than 8; ~19%) ----
#pragma unroll
    for (int r = 0; r < 5; r++) {
        int pr = oo[r + 1] - oo[r];
        const int* sp = srcs + oo[r];
        for (int s8 = 8; s8 < pr; s8 += 8) {
            int4 f0 = *(const int4*)(sp + s8);
            int4 f1 = *(const int4*)(sp + s8 + 4);
            __half2 h0 = tab[f0.x * 16 + p], h1 = tab[f0.y * 16 + p];
            __half2 h2 = tab[f0.z * 16 + p], h3 = tab[f0.w * 16 + p];
            __half2 h4 = tab[f1.x * 16 + p], h5 = tab[f1.y * 16 + p];
            __half2 h6 = tab[f1.z * 16 + p], h7 = tab[f1.w * 16 + p];
            __half2 rb = __hadd2(__hadd2(__hadd2(h0, h1), __hadd2(h2, h3)),
                                 __hadd2(__hadd2(h4, h5), __hadd2(h6, h7)));
            float2 rf = __half22float2(rb);
            Sx[r] += rf.x; Sy[r] += rf.y;
        }
    }
    // ---- per-run comp fold ----
    float a0x = 0.f, a0y = 0.f, a1x = 0.f, a1y = 0.f;
    float a2x = 0.f, a2y = 0.f, a3x = 0.f, a3y = 0.f;
#pragma unroll
    for (int r = 0; r < 5; r++) {
        int cr = cc[r];
        float ic = (cr > 0) ? __builtin_amdgcn_rcpf((float)cr) : 0.f;
        float scx = Sx[r] * ic, scy = Sy[r] * ic;
        float4 cw = (r == 0) ? cw0 : (r == 1) ? cw1 : (r == 2) ? cw2
                  : (r == 3) ? cw3 : cw4;           // resolved at unroll
        a0x += cw.x * scx; a0y += cw.x * scy;
        a1x += cw.y * scx; a1y += cw.y * scy;
        a2x += cw.z * scx; a2y += cw.z * scy;
        a3x += cw.w * scx; a3y += cw.w * scy;
    }
    int nl = wave * 4 + q;
    __half2* row = (__half2*)(sAgg16 + nl * 176);   // k/2 index
    row[p]      = __float22half2_rn(make_float2(a0x, a0y));   // k = 0..31
    row[16 + p] = __float22half2_rn(make_float2(a1x, a1y));   // k = 32..63
    row[32 + p] = __float22half2_rn(make_float2(a2x, a2y));   // k = 64..95
    row[48 + p] = __float22half2_rn(make_float2(a3x, a3y));   // k = 96..127
    row[64 + p] = selfh;                                      // k = 128..159
    __syncthreads();

    // phase 2: [16x160] x [160x32] via 5x mfma_f32_16x16x32_f16 per tile
    if (wave < 2) {
        int lane = t & 63;
        floatx4 acc = {0.f, 0.f, 0.f, 0.f};
        const __half* aBase = sAgg16 + (lane & 15) * 176 + ((lane >> 4) << 3);
        const __half* bBase = Wbl + wave * 512 + lane * 8;
#pragma unroll
        for (int s = 0; s < 5; s++) {
            half8 a = *(const half8*)(aBase + s * 32);
            half8 b = *(const half8*)(bBase + s * 1024);
            acc = __builtin_amdgcn_mfma_f32_16x16x32_f16(a, b, acc, 0, 0, 0);
        }
        int o = wave * 16 + (lane & 15);
        float bi = bias[o];
#pragma unroll
        for (int r = 0; r < 4; r++) {
            int node = blockIdx.x * 16 + ((lane >> 4) << 2) + r;
            hout[node * 32 + o] = __float2half(tanhf(acc[r] + bi));
        }
    }
}

// ---------------- final MLP via MFMA: 16 graphs/block ----------------
static __global__ __launch_bounds__(256) void k_mlp(
    const __half* __restrict__ h1, const __half* __restrict__ h2,
    const __half* __restrict__ h3, const __half* __restrict__ h4,
    const int* __restrict__ uidx, const int* __restrict__ iidx,
    const __half* __restrict__ Wm, const float* __restrict__ b1,
    const float* __restrict__ w2, const float* __restrict__ b2,
    float* __restrict__ out) {
    __shared__ __align__(16) __half sg[16 * 264];   // 8.25 KB
    __shared__ float sacc[4][16];
    int t = threadIdx.x, wave = t >> 6, lane = t & 63;
    int g0 = blockIdx.x * 16;
    int lt = lane >> 4, lp = lane & 15;
    const __half* htab = (lt == 0) ? h1 : (lt == 1) ? h2 : (lt == 2) ? h3 : h4;
#pragma unroll
    for (int gg2 = 0; gg2 < 4; gg2++) {
        int gg = wave * 4 + gg2;
        int g = g0 + gg;
        int u = uidx[g], it = iidx[g];
        __half2* dst = (__half2*)(sg + gg * 264);
        dst[lt * 16 + lp]      = ((const __half2*)(htab + u * 32))[lp];
        dst[64 + lt * 16 + lp] = ((const __half2*)(htab + it * 32))[lp];
    }
    __syncthreads();
    floatx4 acc0 = {0.f, 0.f, 0.f, 0.f}, acc1 = {0.f, 0.f, 0.f, 0.f};
    const __half* aBase = sg + (lane & 15) * 264 + ((lane >> 4) << 3);
    const __half* bB0 = Wm + (wave * 2 + 0) * 4096 + lane * 8;
    const __half* bB1 = Wm + (wave * 2 + 1) * 4096 + lane * 8;
#pragma unroll
    for (int s = 0; s < 8; s++) {
        half8 a  = *(const half8*)(aBase + s * 32);
        half8 f0 = *(const half8*)(bB0 + s * 512);
        half8 f1 = *(const half8*)(bB1 + s * 512);
        acc0 = __builtin_amdgcn_mfma_f32_16x16x32_f16(a, f0, acc0, 0, 0, 0);
        acc1 = __builtin_amdgcn_mfma_f32_16x16x32_f16(a, f1, acc1, 0, 0, 0);
    }
    int o0 = wave * 32 + (lane & 15);
    int o1 = o0 + 16;
    float b10 = b1[o0], b11 = b1[o1], w20 = w2[o0], w21 = w2[o1];
#pragma unroll
    for (int r = 0; r < 4; r++) {
        float z0 = fmaxf(acc0[r] + b10, 0.f);
        float z1 = fmaxf(acc1[r] + b11, 0.f);
        float v = z0 * w20 + z1 * w21;
#pragma unroll
        for (int off = 1; off < 16; off <<= 1) v += __shfl_xor(v, off);
        if ((lane & 15) == 0) sacc[wave][((lane >> 4) << 2) + r] = v;
    }
    __syncthreads();
    if (t < 16)
        out[g0 + t] = sacc[0][t] + sacc[1][t] + sacc[2][t] + sacc[3][t] + b2[0];
}

// ---------------- launcher ----------------
extern "C" void kernel_launch(void* const* d_in, const int* in_sizes, int n_in,
                              void* d_out, int out_size, void* d_ws, size_t ws_size,
                              hipStream_t stream) {
    const float* x  = (const float*)d_in[0];
    const int*   ei = (const int*)d_in[1];
    const int*   et = (const int*)d_in[2];
    const int*   ui = (const int*)d_in[3];
    const int*   ii = (const int*)d_in[4];
    const float* w1 = (const float*)d_in[21];
    const float* b1 = (const float*)d_in[22];
    const float* w2 = (const float*)d_in[23];
    const float* b2 = (const float*)d_in[24];

    // workspace layout (bytes, 128-aligned). Total ~60.2 MB; guard proven in R1.
    char* ws = (char*)d_ws;
    if (ws_size < 92167680UL) return;
    int*    gcur = (int*)(ws + 0);              // [392]
    int*    offs = (int*)(ws + 2048);           // [500000]
    int*    cnt  = (int*)(ws + 2002176);        // [500000]
    int*    srcs = (int*)(ws + 4002304);        // [392*15360] + 16 slack
    __half* Wb   = (__half*)(ws + 28086912);    // [20480] fp16 RGCN B-frags
    __half* Wm   = (__half*)(ws + 28127872);    // [32768] fp16 MLP B-frags
    __half* ht0  = (__half*)(ws + 28193536);    // [100001*32] fp16 dense
    __half* ht1  = (__half*)(ws + 34593664);    // [100001*32]
    __half* ht2  = (__half*)(ws + 40993792);    // [100001*32]
    __half* ht3  = (__half*)(ws + 47393920);    // [100001*32]
    __half* ht4  = (__half*)(ws + 53794048);    // [100001*32], ends 60.2 MB
    // part aliases ht1..ht4 + tail (dead after k_bsort; layers run later)
    unsigned long long* part = (unsigned long long*)(ws + 34593664);  // 32.1 MB

    // k_prep covers: ht0/slack (12501), Wb (80), Wm (128), gcur (1)
    k_prep<<<12710, 256, 0, stream>>>(x, ht0, srcs, gcur,
        (const float*)d_in[5],  (const float*)d_in[7],
        (const float*)d_in[9],  (const float*)d_in[11],
        (const float*)d_in[13], (const float*)d_in[15],
        (const float*)d_in[17], (const float*)d_in[19], w1, Wb, Wm);
    k_part<<<(N_EDGES + PTILE - 1) / PTILE, 256, 0, stream>>>(ei, et, gcur, part);
    k_bsort<<<NBUCK, 1024, 0, stream>>>(part, gcur, offs, cnt, srcs,
                                        ht1, ht2, ht3, ht4);

    __half* tabs[5] = {ht0, ht1, ht2, ht3, ht4};
    for (int l = 0; l < 4; l++) {
        const float* comp = (const float*)d_in[6 + 4 * l];
        const float* bias = (const float*)d_in[8 + 4 * l];
        k_layer<<<6250, 256, 0, stream>>>((const __half2*)tabs[l], offs, cnt,
                                          srcs, comp, Wb + l * 5120, bias,
                                          tabs[l + 1]);
    }
    k_mlp<<<256, 256, 0, stream>>>(ht1, ht2, ht3, ht4, ui, ii, Wm, b1, w2, b2,
                                   (float*)d_out);
}

// Round 17
// 371.621 us; speedup vs baseline: 1.9485x; 1.4339x over previous
//
#include <hip/hip_runtime.h>
#include <hip/hip_bf16.h>
#include <hip/hip_fp16.h>

#define N_NODES 100000
#define N_EDGES 3200000
#define N_GRAPHS 4096
#define N_REL 5
#define N_BASES 4
#define HID 32
#define SEG (N_NODES*N_REL)
#define DUMMY N_NODES            // extra node whose fp16 feature row is all-zero

#define NBUCK 392                // buckets of 256 dst nodes
#define BCAP  10240              // part-record capacity per bucket (mean 8163)
#define PBCAP 15360              // padded srcs capacity per bucket (mean ~12.9K)
#define NKEY  1280               // 256 nodes * 5 rels
#define PTILE 4096               // edges per k_part block (32 KB stage -> 4 blocks/CU)

typedef _Float16 half8 __attribute__((ext_vector_type(8)));
typedef float floatx4 __attribute__((ext_vector_type(4)));

// ---------------- CSR pass 1: partition edges into dst-range buckets ----------------
static __global__ __launch_bounds__(256) void k_part(const int* __restrict__ ei,
                                                     const int* __restrict__ et,
                                                     int* __restrict__ gcur,
                                                     unsigned long long* __restrict__ part) {
    __shared__ unsigned long long stage[PTILE];     // 32 KB
    __shared__ int hist[NBUCK];
    __shared__ int lofs[NBUCK];
    __shared__ int lbase[NBUCK];
    __shared__ int sscan[256];
    int t = threadIdx.x;
    int e0 = blockIdx.x * PTILE;
    int tile_n = N_EDGES - e0; if (tile_n > PTILE) tile_n = PTILE;

    for (int k = t; k < NBUCK; k += 256) hist[k] = 0;
    __syncthreads();
    // pass A: load 16 edges/thread into registers + LDS histogram
    int src[16], bkt[16], lkey[16];
#pragma unroll
    for (int j = 0; j < 16; j++) {
        int e = e0 + j * 256 + t;
        if (e < N_EDGES) {
            int s = ei[e];
            int d = ei[N_EDGES + e];
            int r = et[e];
            src[j] = s; bkt[j] = d >> 8; lkey[j] = ((d & 255) * 5) + r;
            atomicAdd(&hist[bkt[j]], 1);
        } else bkt[j] = -1;
    }
    __syncthreads();
    // exclusive scan over 392 buckets: thread t owns slots 2t, 2t+1
    int h0 = (2 * t     < NBUCK) ? hist[2 * t]     : 0;
    int h1 = (2 * t + 1 < NBUCK) ? hist[2 * t + 1] : 0;
    int s2 = h0 + h1;
    sscan[t] = s2;
    __syncthreads();
    for (int off = 1; off < 256; off <<= 1) {
        int xv = (t >= off) ? sscan[t - off] : 0;
        __syncthreads();
        sscan[t] += xv;
        __syncthreads();
    }
    int excl = sscan[t] - s2;
    if (2 * t     < NBUCK) lofs[2 * t]     = excl;
    if (2 * t + 1 < NBUCK) lofs[2 * t + 1] = excl + h0;
    for (int k = t; k < NBUCK; k += 256) lbase[k] = atomicAdd(&gcur[k], hist[k]);
    __syncthreads();
    for (int k = t; k < NBUCK; k += 256) hist[k] = 0;   // reuse as cursor
    __syncthreads();
    // pass B: scatter registers into bucket-ordered LDS staging
#pragma unroll
    for (int j = 0; j < 16; j++) {
        if (bkt[j] >= 0) {
            int rank = atomicAdd(&hist[bkt[j]], 1);
            stage[lofs[bkt[j]] + rank] =
                ((unsigned long long)(unsigned)((bkt[j] << 16) | lkey[j]) << 32)
                | (unsigned)src[j];
        }
    }
    __syncthreads();
    // pass C: sequential copy-out — per-bucket runs land coalesced
    for (int i = t; i < tile_n; i += 256) {
        unsigned long long u = stage[i];
        unsigned hi = (unsigned)(u >> 32);
        int bb = hi >> 16;
        unsigned long long lk = hi & 0xFFFFu;
        int pos = lbase[bb] + (i - lofs[bb]);
        if (pos < BCAP)
            part[(size_t)bb * BCAP + pos] = (lk << 32) | (u & 0xffffffffULL);
    }
}

// ---------------- CSR pass 2: per-bucket counting sort, runs PADDED to 8 ----------------
// Block 0 additionally writes the ht1..ht4 DUMMY rows at the END — part
// aliases ht1..ht4, so these zero rows must land only after part is consumed.
static __global__ __launch_bounds__(1024) void k_bsort(const unsigned long long* __restrict__ part,
                                                       const int* __restrict__ gcur,
                                                       int* __restrict__ offs,
                                                       int* __restrict__ cnt,
                                                       int* __restrict__ srcs,
                                                       __half* __restrict__ ht1,
                                                       __half* __restrict__ ht2,
                                                       __half* __restrict__ ht3,
                                                       __half* __restrict__ ht4) {
    __shared__ int lhist[NKEY];      // 5 KB
    __shared__ int lscan[NKEY];      // 5 KB
    __shared__ int sscan[256];       // 1 KB
    __shared__ int lsrc[PBCAP];      // 60 KB
    int b = blockIdx.x;
    int t = threadIdx.x;
    int n = gcur[b]; if (n > BCAP) n = BCAP;
    const unsigned long long* reg = part + (size_t)b * BCAP;

    for (int k = t; k < NKEY; k += 1024) lhist[k] = 0;
    __syncthreads();
    for (int i = t; i < n; i += 1024)
        atomicAdd(&lhist[(int)(reg[i] >> 32)], 1);
    __syncthreads();

    // exclusive scan over PADDED counts (1280 = 256 threads x 5 keys)
    int loc[5]; int s5 = 0;
    if (t < 256) {
#pragma unroll
        for (int j = 0; j < 5; j++) { loc[j] = s5; s5 += (lhist[t * 5 + j] + 7) & ~7; }
        sscan[t] = s5;
    }
    __syncthreads();
    for (int off = 1; off < 256; off <<= 1) {
        int x = (t >= off && t < 256) ? sscan[t - off] : 0;
        __syncthreads();
        if (t < 256) sscan[t] += x;
        __syncthreads();
    }
    if (t < 256) {
        int excl = sscan[t] - s5;
#pragma unroll
        for (int j = 0; j < 5; j++) lscan[t * 5 + j] = excl + loc[j];
    }
    __syncthreads();
    int ptot = sscan[255]; if (ptot > PBCAP) ptot = PBCAP;
    int pout = ptot + 16; if (pout > PBCAP) pout = PBCAP;

    int base = b * PBCAP;
    if (t < 256) {
#pragma unroll
        for (int j = 0; j < 5; j++) {
            int k = t * 5 + j;
            int segid = b * NKEY + k;
            if (segid < SEG) {
                cnt[segid]  = lhist[k];
                offs[segid] = base + lscan[k];
            }
        }
    }
    __syncthreads();
    // reset cursors + dummy-fill the written region
    for (int k = t; k < NKEY; k += 1024) lhist[k] = 0;
    for (int i = t; i < pout; i += 1024) lsrc[i] = DUMMY;
    __syncthreads();
    for (int i = t; i < n; i += 1024) {
        unsigned long long u = reg[i];
        int k = (int)(u >> 32);
        int pos = lscan[k] + atomicAdd(&lhist[k], 1);
        if (pos < PBCAP) lsrc[pos] = (int)(u & 0xffffffffULL);
    }
    __syncthreads();
    for (int i = t; i < pout; i += 1024) srcs[base + i] = lsrc[i];

    // ht1..ht4 DUMMY rows — safe here: part reads are done; layers run later.
    if (b == 0 && t < 128) {
        __half* hp = (t < 32) ? ht1 : (t < 64) ? ht2 : (t < 96) ? ht3 : ht4;
        hp[N_NODES * 32 + (t & 31)] = __float2half(0.f);
    }
}

// ---------------- fused prep: x->ht0 (+its dummy row), srcs slack, gcur zero,
// ---------------- RGCN B-frags (Wb), MLP B-frags (Wm) — one launch ----------------
static __global__ __launch_bounds__(256) void k_prep(
    const float* __restrict__ x, __half* __restrict__ ht0,
    int* __restrict__ srcs, int* __restrict__ gcur,
    const float* __restrict__ ba0, const float* __restrict__ ro0,
    const float* __restrict__ ba1, const float* __restrict__ ro1,
    const float* __restrict__ ba2, const float* __restrict__ ro2,
    const float* __restrict__ ba3, const float* __restrict__ ro3,
    const float* __restrict__ w1, __half* __restrict__ Wb,
    __half* __restrict__ Wm) {
    int blk = blockIdx.x;
    int t = threadIdx.x;
    if (blk < 12501) {                              // ht0 + its dummy row + slack
        int tid = blk * 256 + t;
        if (tid < (N_NODES + 1) * 32) {
            int nd = tid >> 5, ii = tid & 31;
            float v = (nd < N_NODES && ii < 4) ? x[(nd << 2) + ii] : 0.f;
            ht0[tid] = __float2half(v);
        } else {
            int r = tid - (N_NODES + 1) * 32;
            if (r < 16) srcs[NBUCK * PBCAP + r] = DUMMY;   // global slack
        }
    } else if (blk < 12581) {                       // Wb: 80 blocks = 20480
        int idx = (blk - 12501) * 256 + t;
        int j    = idx & 7;
        int lane = (idx >> 3) & 63;
        int tile = (idx >> 9) & 1;
        int ls   = idx >> 10;                       // l*5 + s, < 20
        int l    = ls / 5;
        int s    = ls - l * 5;
        const float* basis = (l == 0) ? ba0 : (l == 1) ? ba1 : (l == 2) ? ba2 : ba3;
        const float* root  = (l == 0) ? ro0 : (l == 1) ? ro1 : (l == 2) ? ro2 : ro3;
        int in_c = (l == 0) ? 4 : HID;
        int k = s * 32 + ((lane >> 4) << 3) + j;
        int o = tile * 16 + (lane & 15);
        float v;
        if (k < 128) {
            int b = k >> 5, ii = k & 31;
            v = (ii < in_c) ? basis[(b * in_c + ii) * HID + o] : 0.f;
        } else {
            int ii = k - 128;
            v = (ii < in_c) ? root[ii * HID + o] : 0.f;
        }
        Wb[idx] = __float2half(v);
    } else if (blk < 12709) {                       // Wm: 128 blocks = 32768
        int idx = (blk - 12581) * 256 + t;
        int j    = idx & 7;
        int lane = (idx >> 3) & 63;
        int s    = (idx >> 9) & 7;
        int tile = idx >> 12;
        int k = s * 32 + ((lane >> 4) << 3) + j;
        int o = tile * 16 + (lane & 15);
        Wm[idx] = __float2half(w1[k * 128 + o]);
    } else {                                        // gcur zero
        for (int k = t; k < NBUCK; k += 256) gcur[k] = 0;
    }
}

// ---------------- fused RGCN layer ----------------
// R15/R16 lesson: int4 e0[5]/Sx[5] arrays never got SROA'd (the dynamic-trip
// residual loop blocked full unroll) -> alloca -> 170-300 MB scratch traffic.
// This version uses NAMED SCALARS ONLY (no arrays) in straight-line code: the
// 40 first-batch gathers sit in one basic block, so the scheduler can hoist
// all their loads (the latency-overlap goal) and nothing can spill to scratch.
#define G8SUM(SX, SY, EA, EB) { \
    __half2 g0 = tab[(EA).x * 16 + p], g1 = tab[(EA).y * 16 + p]; \
    __half2 g2 = tab[(EA).z * 16 + p], g3 = tab[(EA).w * 16 + p]; \
    __half2 g4 = tab[(EB).x * 16 + p], g5 = tab[(EB).y * 16 + p]; \
    __half2 g6 = tab[(EB).z * 16 + p], g7 = tab[(EB).w * 16 + p]; \
    __half2 sb = __hadd2(__hadd2(__hadd2(g0, g1), __hadd2(g2, g3)), \
                         __hadd2(__hadd2(g4, g5), __hadd2(g6, g7))); \
    float2 bf = __half22float2(sb); SX = bf.x; SY = bf.y; }

#define RESID(SX, SY, OA, OB) { \
    int pr = (OB) - (OA); \
    const int* sp = srcs + (OA); \
    for (int s8 = 8; s8 < pr; s8 += 8) { \
        int4 f0 = *(const int4*)(sp + s8); \
        int4 f1 = *(const int4*)(sp + s8 + 4); \
        __half2 h0 = tab[f0.x * 16 + p], h1 = tab[f0.y * 16 + p]; \
        __half2 h2 = tab[f0.z * 16 + p], h3 = tab[f0.w * 16 + p]; \
        __half2 h4 = tab[f1.x * 16 + p], h5 = tab[f1.y * 16 + p]; \
        __half2 h6 = tab[f1.z * 16 + p], h7 = tab[f1.w * 16 + p]; \
        __half2 rb = __hadd2(__hadd2(__hadd2(h0, h1), __hadd2(h2, h3)), \
                             __hadd2(__hadd2(h4, h5), __hadd2(h6, h7))); \
        float2 rf = __half22float2(rb); \
        SX += rf.x; SY += rf.y; } }

#define FOLD(SX, SY, CR, CW) { \
    float ic = ((CR) > 0) ? __builtin_amdgcn_rcpf((float)(CR)) : 0.f; \
    float scx = (SX) * ic, scy = (SY) * ic; \
    a0x += (CW).x * scx; a0y += (CW).x * scy; \
    a1x += (CW).y * scx; a1y += (CW).y * scy; \
    a2x += (CW).z * scx; a2y += (CW).z * scy; \
    a3x += (CW).w * scx; a3y += (CW).w * scy; }

static __global__ __launch_bounds__(256, 4) void k_layer(
    const __half2* __restrict__ tab, const int* __restrict__ offs,
    const int* __restrict__ cnt, const int* __restrict__ srcs,
    const float* __restrict__ comp, const __half* __restrict__ Wbl,
    const float* __restrict__ bias, __half* __restrict__ hout) {
    __shared__ __align__(16) __half sAgg16[16 * 176];   // 5.5 KB
    int t = threadIdx.x;
    int wave = t >> 6, q = (t >> 4) & 3, p = t & 15;

    float4 cw0 = *(const float4*)(comp + 0);        // SGPR-resident
    float4 cw1 = *(const float4*)(comp + 4);
    float4 cw2 = *(const float4*)(comp + 8);
    float4 cw3 = *(const float4*)(comp + 12);
    float4 cw4 = *(const float4*)(comp + 16);

    int n = blockIdx.x * 16 + wave * 4 + q;         // N_NODES = 6250*16
    int s5 = n * N_REL;
    int oo0 = offs[s5], oo1 = offs[s5 + 1], oo2 = offs[s5 + 2];
    int oo3 = offs[s5 + 3], oo4 = offs[s5 + 4];
    int cc0 = cnt[s5], cc1 = cnt[s5 + 1], cc2 = cnt[s5 + 2];
    int cc3 = cnt[s5 + 3], cc4 = cnt[s5 + 4];
    int oo5 = oo4 + ((cc4 + 7) & ~7);               // padded end

    __half2 selfh = tab[n * 16 + p];

    // ---- first batches of ALL 5 runs: 10 independent dwordx4 srcs loads ----
    const int4* q0 = (const int4*)(srcs + oo0);
    const int4* q1 = (const int4*)(srcs + oo1);
    const int4* q2 = (const int4*)(srcs + oo2);
    const int4* q3 = (const int4*)(srcs + oo3);
    const int4* q4 = (const int4*)(srcs + oo4);
    int4 e00 = q0[0], e01 = q0[1];
    int4 e10 = q1[0], e11 = q1[1];
    int4 e20 = q2[0], e21 = q2[1];
    int4 e30 = q3[0], e31 = q3[1];
    int4 e40 = q4[0], e41 = q4[1];

    // ---- 40 gathers in one basic block (scheduler hoists the loads) ----
    float Sx0, Sy0, Sx1, Sy1, Sx2, Sy2, Sx3, Sy3, Sx4, Sy4;
    G8SUM(Sx0, Sy0, e00, e01);
    G8SUM(Sx1, Sy1, e10, e11);
    G8SUM(Sx2, Sy2, e20, e21);
    G8SUM(Sx3, Sy3, e30, e31);
    G8SUM(Sx4, Sy4, e40, e41);

    // ---- residual batches (runs longer than 8; ~19%) ----
    RESID(Sx0, Sy0, oo0, oo1);
    RESID(Sx1, Sy1, oo1, oo2);
    RESID(Sx2, Sy2, oo2, oo3);
    RESID(Sx3, Sy3, oo3, oo4);
    RESID(Sx4, Sy4, oo4, oo5);

    // ---- per-run comp fold ----
    float a0x = 0.f, a0y = 0.f, a1x = 0.f, a1y = 0.f;
    float a2x = 0.f, a2y = 0.f, a3x = 0.f, a3y = 0.f;
    FOLD(Sx0, Sy0, cc0, cw0);
    FOLD(Sx1, Sy1, cc1, cw1);
    FOLD(Sx2, Sy2, cc2, cw2);
    FOLD(Sx3, Sy3, cc3, cw3);
    FOLD(Sx4, Sy4, cc4, cw4);

    int nl = wave * 4 + q;
    __half2* row = (__half2*)(sAgg16 + nl * 176);   // k/2 index
    row[p]      = __float22half2_rn(make_float2(a0x, a0y));   // k = 0..31
    row[16 + p] = __float22half2_rn(make_float2(a1x, a1y));   // k = 32..63
    row[32 + p] = __float22half2_rn(make_float2(a2x, a2y));   // k = 64..95
    row[48 + p] = __float22half2_rn(make_float2(a3x, a3y));   // k = 96..127
    row[64 + p] = selfh;                                      // k = 128..159
    __syncthreads();

    // phase 2: [16x160] x [160x32] via 5x mfma_f32_16x16x32_f16 per tile
    if (wave < 2) {
        int lane = t & 63;
        floatx4 acc = {0.f, 0.f, 0.f, 0.f};
        const __half* aBase = sAgg16 + (lane & 15) * 176 + ((lane >> 4) << 3);
        const __half* bBase = Wbl + wave * 512 + lane * 8;
#pragma unroll
        for (int s = 0; s < 5; s++) {
            half8 a = *(const half8*)(aBase + s * 32);
            half8 b = *(const half8*)(bBase + s * 1024);
            acc = __builtin_amdgcn_mfma_f32_16x16x32_f16(a, b, acc, 0, 0, 0);
        }
        int o = wave * 16 + (lane & 15);
        float bi = bias[o];
#pragma unroll
        for (int r = 0; r < 4; r++) {
            int node = blockIdx.x * 16 + ((lane >> 4) << 2) + r;
            hout[node * 32 + o] = __float2half(tanhf(acc[r] + bi));
        }
    }
}

// ---------------- final MLP via MFMA: 16 graphs/block ----------------
static __global__ __launch_bounds__(256) void k_mlp(
    const __half* __restrict__ h1, const __half* __restrict__ h2,
    const __half* __restrict__ h3, const __half* __restrict__ h4,
    const int* __restrict__ uidx, const int* __restrict__ iidx,
    const __half* __restrict__ Wm, const float* __restrict__ b1,
    const float* __restrict__ w2, const float* __restrict__ b2,
    float* __restrict__ out) {
    __shared__ __align__(16) __half sg[16 * 264];   // 8.25 KB
    __shared__ float sacc[4][16];
    int t = threadIdx.x, wave = t >> 6, lane = t & 63;
    int g0 = blockIdx.x * 16;
    int lt = lane >> 4, lp = lane & 15;
    const __half* htab = (lt == 0) ? h1 : (lt == 1) ? h2 : (lt == 2) ? h3 : h4;
#pragma unroll
    for (int gg2 = 0; gg2 < 4; gg2++) {
        int gg = wave * 4 + gg2;
        int g = g0 + gg;
        int u = uidx[g], it = iidx[g];
        __half2* dst = (__half2*)(sg + gg * 264);
        dst[lt * 16 + lp]      = ((const __half2*)(htab + u * 32))[lp];
        dst[64 + lt * 16 + lp] = ((const __half2*)(htab + it * 32))[lp];
    }
    __syncthreads();
    floatx4 acc0 = {0.f, 0.f, 0.f, 0.f}, acc1 = {0.f, 0.f, 0.f, 0.f};
    const __half* aBase = sg + (lane & 15) * 264 + ((lane >> 4) << 3);
    const __half* bB0 = Wm + (wave * 2 + 0) * 4096 + lane * 8;
    const __half* bB1 = Wm + (wave * 2 + 1) * 4096 + lane * 8;
#pragma unroll
    for (int s = 0; s < 8; s++) {
        half8 a  = *(const half8*)(aBase + s * 32);
        half8 f0 = *(const half8*)(bB0 + s * 512);
        half8 f1 = *(const half8*)(bB1 + s * 512);
        acc0 = __builtin_amdgcn_mfma_f32_16x16x32_f16(a, f0, acc0, 0, 0, 0);
        acc1 = __builtin_amdgcn_mfma_f32_16x16x32_f16(a, f1, acc1, 0, 0, 0);
    }
    int o0 = wave * 32 + (lane & 15);
    int o1 = o0 + 16;
    float b10 = b1[o0], b11 = b1[o1], w20 = w2[o0], w21 = w2[o1];
#pragma unroll
    for (int r = 0; r < 4; r++) {
        float z0 = fmaxf(acc0[r] + b10, 0.f);
        float z1 = fmaxf(acc1[r] + b11, 0.f);
        float v = z0 * w20 + z1 * w21;
#pragma unroll
        for (int off = 1; off < 16; off <<= 1) v += __shfl_xor(v, off);
        if ((lane & 15) == 0) sacc[wave][((lane >> 4) << 2) + r] = v;
    }
    __syncthreads();
    if (t < 16)
        out[g0 + t] = sacc[0][t] + sacc[1][t] + sacc[2][t] + sacc[3][t] + b2[0];
}

// ---------------- launcher ----------------
extern "C" void kernel_launch(void* const* d_in, const int* in_sizes, int n_in,
                              void* d_out, int out_size, void* d_ws, size_t ws_size,
                              hipStream_t stream) {
    const float* x  = (const float*)d_in[0];
    const int*   ei = (const int*)d_in[1];
    const int*   et = (const int*)d_in[2];
    const int*   ui = (const int*)d_in[3];
    const int*   ii = (const int*)d_in[4];
    const float* w1 = (const float*)d_in[21];
    const float* b1 = (const float*)d_in[22];
    const float* w2 = (const float*)d_in[23];
    const float* b2 = (const float*)d_in[24];

    // workspace layout (bytes, 128-aligned). Total ~60.2 MB; guard proven in R1.
    char* ws = (char*)d_ws;
    if (ws_size < 92167680UL) return;
    int*    gcur = (int*)(ws + 0);              // [392]
    int*    offs = (int*)(ws + 2048);           // [500000]
    int*    cnt  = (int*)(ws + 2002176);        // [500000]
    int*    srcs = (int*)(ws + 4002304);        // [392*15360] + 16 slack
    __half* Wb   = (__half*)(ws + 28086912);    // [20480] fp16 RGCN B-frags
    __half* Wm   = (__half*)(ws + 28127872);    // [32768] fp16 MLP B-frags
    __half* ht0  = (__half*)(ws + 28193536);    // [100001*32] fp16 dense
    __half* ht1  = (__half*)(ws + 34593664);    // [100001*32]
    __half* ht2  = (__half*)(ws + 40993792);    // [100001*32]
    __half* ht3  = (__half*)(ws + 47393920);    // [100001*32]
    __half* ht4  = (__half*)(ws + 53794048);    // [100001*32], ends 60.2 MB
    // part aliases ht1..ht4 + tail (dead after k_bsort; layers run later)
    unsigned long long* part = (unsigned long long*)(ws + 34593664);  // 32.1 MB

    // k_prep covers: ht0/slack (12501), Wb (80), Wm (128), gcur (1)
    k_prep<<<12710, 256, 0, stream>>>(x, ht0, srcs, gcur,
        (const float*)d_in[5],  (const float*)d_in[7],
        (const float*)d_in[9],  (const float*)d_in[11],
        (const float*)d_in[13], (const float*)d_in[15],
        (const float*)d_in[17], (const float*)d_in[19], w1, Wb, Wm);
    k_part<<<(N_EDGES + PTILE - 1) / PTILE, 256, 0, stream>>>(ei, et, gcur, part);
    k_bsort<<<NBUCK, 1024, 0, stream>>>(part, gcur, offs, cnt, srcs,
                                        ht1, ht2, ht3, ht4);

    __half* tabs[5] = {ht0, ht1, ht2, ht3, ht4};
    for (int l = 0; l < 4; l++) {
        const float* comp = (const float*)d_in[6 + 4 * l];
        const float* bias = (const float*)d_in[8 + 4 * l];
        k_layer<<<6250, 256, 0, stream>>>((const __half2*)tabs[l], offs, cnt,
                                          srcs, comp, Wb + l * 5120, bias,
                                          tabs[l + 1]);
    }
    k_mlp<<<256, 256, 0, stream>>>(ht1, ht2, ht3, ht4, ui, ii, Wm, b1, w2, b2,
                                   (float*)d_out);
}